// Round 9
// baseline (58.292 us; speedup 1.0000x reference)
//
#include <hip/hip_runtime.h>

// feature_map: (B=16, H=27, W=48, C=512) fp32
// nmses:       (B=16, R=100, 4) fp32  (cx, cy, w, h in pixels)
// output:      (B, R, 7, 7, C) fp32
#define BB   16
#define RR   100
#define HH   27
#define WW   48
#define CC   512
#define PP   7

#define C4    (CC / 4)           // 128 float4 per pixel
#define ROW4  (WW * C4)          // 6144 float4 per (b,y)
#define IMG4  (HH * ROW4)        // 165888 float4 per b

#define NBOX  (BB * RR)          // 1600 boxes
#define NBLK  (NBOX * PP)        // 11200 blocks: one per (box, px)
#define NXCD  8
#define YMAX  15                 // max row span: h<=208 -> ystep<=2.09 -> <=15

typedef float vf4 __attribute__((ext_vector_type(4)));

// Block = (box, px). Stage pixel-columns [xbase, xbase+1] (contiguous 4KB/row)
// for rows [ylo..yhi] into LDS once; 7 waves (one per py) consume 4 corners
// each from LDS. Converts ~56KB of TCP demand-reads per block into ~34KB of
// unique staged bytes + LDS-pipe reads (separate 128B/cy path, conflict-free).
__global__ __launch_bounds__(448) void roi_stage_kernel(
    const float* __restrict__ fm,
    const float* __restrict__ nms,
    float* __restrict__ out)
{
    __shared__ vf4 st[YMAX][2][C4];          // 15*2*128*16B = 60 KB

    // XCD-aware bijective swizzle (11200 % 8 == 0): contiguous box ranges
    // per XCD keep the active image slice in that XCD's private L2.
    const int bid = blockIdx.x;
    const int wg  = (bid % NXCD) * (NBLK / NXCD) + bid / NXCD;

    const int px = wg % PP;                  // block-uniform
    const int t  = wg / PP;                  // box index (b*R + r)
    const int b  = t / RR;

    const vf4 box = ((const vf4*)nms)[t];    // block-uniform -> scalar load
    const float cx = box.x, cy = box.y, w = box.z, h = box.w;

    // Reference op order preserved EXACTLY (mask boundary is discontinuous,
    // so float rounding must match the passing kernels).
    const float x1 = (cx - w * 0.5f) / 768.0f;
    const float x2 = (cx + w * 0.5f) / 768.0f;
    const float y1 = (cy - h * 0.5f) / 432.0f;
    const float y2 = (cy + h * 0.5f) / 432.0f;

    const float xs = x1 * 47.0f + (float)px * (x2 - x1) * 47.0f / 6.0f;
    const bool  vx = (xs >= 0.0f) && (xs <= 47.0f);

    const int tid  = threadIdx.x;
    const int lane = tid & 63;
    const int wid  = tid >> 6;               // this wave's py (0..6)

    // x columns (block-uniform)
    const float x0f = floorf(xs);
    const float lx  = xs - x0f;
    int x0 = (int)x0f; x0 = min(max(x0, 0), WW - 1);
    const int x1i   = min(x0 + 1, WW - 1);
    const int xbase = min(x0, WW - 2);       // stage [xbase, xbase+1]
    const int sx0   = x0  - xbase;           // 0 or 1 (1 only at right clip)
    const int sx1   = x1i - xbase;

    // y row span across py=0..6 (ys monotone increasing in py since h>0).
    // Endpoint formulas use the same associativity as the per-wave formula.
    const float ysA = y1 * 26.0f + 0.0f * (y2 - y1) * 26.0f / 6.0f;
    const float ysB = y1 * 26.0f + 6.0f * (y2 - y1) * 26.0f / 6.0f;
    int ylo = (int)floorf(ysA); ylo = min(max(ylo, 0), HH - 1);
    int yhi = (int)floorf(ysB); yhi = min(max(yhi, 0), HH - 1);
    yhi = min(yhi + 1, HH - 1);
    const int yspan = yhi - ylo + 1;         // 1..15

    if (vx) {   // block-uniform -> no divergence at the barrier
        const vf4* src = ((const vf4*)fm) + (size_t)b * IMG4
                         + (size_t)ylo * ROW4 + (size_t)xbase * C4;
        const int n4 = yspan * 256;          // 2 cols * 128 float4 per row
        vf4* dst = &st[0][0][0];
        for (int i = tid; i < n4; i += 448) {
            const int r = i >> 8;            // staged row
            const int j = i & 255;           // float4 within the 4KB row pair
            dst[i] = src[(size_t)r * ROW4 + j];
        }
    }
    __syncthreads();

    // Compute phase: wave `wid` handles cell (t, py=wid, px).
    const float ys = y1 * 26.0f + (float)wid * (y2 - y1) * 26.0f / 6.0f;
    const bool  vy = (ys >= 0.0f) && (ys <= 26.0f);

    vf4 o0, o1;
    if (vx && vy) {
        const float y0f = floorf(ys);
        const float ly  = ys - y0f;
        int y0 = (int)y0f; y0 = min(max(y0, 0), HH - 1);
        const int y1r = min(y0 + 1, HH - 1);
        const int r0  = y0  - ylo;           // in [0, yspan)
        const int r1  = y1r - ylo;           // in [0, yspan)

        const vf4 tl0 = st[r0][sx0][lane];
        const vf4 tr0 = st[r0][sx1][lane];
        const vf4 bl0 = st[r1][sx0][lane];
        const vf4 br0 = st[r1][sx1][lane];
        const vf4 tl1 = st[r0][sx0][lane + 64];
        const vf4 tr1 = st[r0][sx1][lane + 64];
        const vf4 bl1 = st[r1][sx0][lane + 64];
        const vf4 br1 = st[r1][sx1][lane + 64];

        const vf4 top0 = tl0 + (tr0 - tl0) * lx;
        const vf4 bot0 = bl0 + (br0 - bl0) * lx;
        o0 = top0 + (bot0 - top0) * ly;
        const vf4 top1 = tl1 + (tr1 - tl1) * lx;
        const vf4 bot1 = bl1 + (br1 - bl1) * lx;
        o1 = top1 + (bot1 - top1) * ly;
    } else {
        o0 = (vf4)(0.0f);
        o1 = (vf4)(0.0f);
    }

    // NT stores won the R6 A/B: keep them. 2KB contiguous per wave.
    const int cell = t * (PP * PP) + wid * PP + px;
    vf4* op = ((vf4*)out) + (size_t)cell * C4 + lane;
    __builtin_nontemporal_store(o0, op);
    __builtin_nontemporal_store(o1, op + 64);
}

extern "C" void kernel_launch(void* const* d_in, const int* in_sizes, int n_in,
                              void* d_out, int out_size, void* d_ws, size_t ws_size,
                              hipStream_t stream)
{
    const float* fm  = (const float*)d_in[0];
    const float* nms = (const float*)d_in[1];
    float* out = (float*)d_out;

    roi_stage_kernel<<<NBLK, 448, 0, stream>>>(fm, nms, out);
}

// Round 10
// 50.950 us; speedup vs baseline: 1.1441x; 1.1441x over previous
//
#include <hip/hip_runtime.h>

// feature_map: (B=16, H=27, W=48, C=512) fp32
// nmses:       (B=16, R=100, 4) fp32  (cx, cy, w, h in pixels)
// output:      (B, R, 7, 7, C) fp32
#define BB   16
#define RR   100
#define HH   27
#define WW   48
#define CC   512
#define PP   7

#define C4    (CC / 4)           // 128 float4 per pixel
#define ROW4  (WW * C4)          // 6144 float4 per (b,y)
#define IMG4  (HH * ROW4)        // 165888 float4 per b

#define NBOX  (BB * RR)          // 1600 boxes
#define NBLK  (NBOX * PP)        // 11200 blocks: one per (box, px)
#define NXCD  8
#define YMAX  9                  // staged rows cap: 9*2*128*16B = 36 KB LDS
                                 // -> 4 blocks/CU (144KB LDS, 28/32 waves)

typedef float vf4 __attribute__((ext_vector_type(4)));

// Block = (box, px), 448 threads (7 waves, one per py).
// Stage pixel-columns [xbase, xbase+1] for up to YMAX rows starting at ylo
// into LDS once; corners in rows beyond the staged range fall back to direct
// global loads (wave-uniform branch; identical to the R5-winning path).
__global__ __launch_bounds__(448) void roi_stage_kernel(
    const float* __restrict__ fm,
    const float* __restrict__ nms,
    float* __restrict__ out)
{
    __shared__ vf4 st[YMAX][2][C4];          // 36 KB

    // XCD-aware bijective swizzle (11200 % 8 == 0).
    const int bid = blockIdx.x;
    const int wg  = (bid % NXCD) * (NBLK / NXCD) + bid / NXCD;

    const int px = wg % PP;                  // block-uniform
    const int t  = wg / PP;                  // box index (b*R + r)
    const int b  = t / RR;

    const vf4 box = ((const vf4*)nms)[t];    // block-uniform -> scalar load
    const float cx = box.x, cy = box.y, w = box.z, h = box.w;

    // Reference op order preserved EXACTLY (mask boundary is discontinuous,
    // so float rounding must match the passing kernels).
    const float x1 = (cx - w * 0.5f) / 768.0f;
    const float x2 = (cx + w * 0.5f) / 768.0f;
    const float y1 = (cy - h * 0.5f) / 432.0f;
    const float y2 = (cy + h * 0.5f) / 432.0f;

    const float xs = x1 * 47.0f + (float)px * (x2 - x1) * 47.0f / 6.0f;
    const bool  vx = (xs >= 0.0f) && (xs <= 47.0f);

    const int tid  = threadIdx.x;
    const int lane = tid & 63;
    const int wid  = tid >> 6;               // this wave's py (0..6)

    // x columns (block-uniform)
    const float x0f = floorf(xs);
    const float lx  = xs - x0f;
    int x0 = (int)x0f; x0 = min(max(x0, 0), WW - 1);
    const int x1i   = min(x0 + 1, WW - 1);
    const int xbase = min(x0, WW - 2);       // stage [xbase, xbase+1]
    const int sx0   = x0  - xbase;           // 0 or 1 (1 only at right clip)
    const int sx1   = x1i - xbase;

    // y row span across py=0..6 (ys monotone in py; same associativity).
    const float ysA = y1 * 26.0f + 0.0f * (y2 - y1) * 26.0f / 6.0f;
    const float ysB = y1 * 26.0f + 6.0f * (y2 - y1) * 26.0f / 6.0f;
    int ylo = (int)floorf(ysA); ylo = min(max(ylo, 0), HH - 1);
    int yhi = (int)floorf(ysB); yhi = min(max(yhi, 0), HH - 1);
    yhi = min(yhi + 1, HH - 1);
    const int yspan = yhi - ylo + 1;         // 1..15
    const int nst   = min(yspan, YMAX);      // rows actually staged

    const vf4* img = ((const vf4*)fm) + (size_t)b * IMG4;

    if (vx) {   // block-uniform -> no divergence at the barrier
        const vf4* src = img + (size_t)ylo * ROW4 + (size_t)xbase * C4;
        const int n4 = nst * 256;            // 2 cols * 128 float4 per row
        vf4* dst = &st[0][0][0];
        for (int i = tid; i < n4; i += 448) {
            const int r = i >> 8;            // staged row
            const int j = i & 255;           // float4 within the 4KB row pair
            dst[i] = src[(size_t)r * ROW4 + j];
        }
    }
    __syncthreads();

    // Compute phase: wave `wid` handles cell (t, py=wid, px).
    const float ys = y1 * 26.0f + (float)wid * (y2 - y1) * 26.0f / 6.0f;
    const bool  vy = (ys >= 0.0f) && (ys <= 26.0f);

    vf4 o0, o1;
    if (vx && vy) {
        const float y0f = floorf(ys);
        const float ly  = ys - y0f;
        int y0 = (int)y0f; y0 = min(max(y0, 0), HH - 1);
        const int y1r = min(y0 + 1, HH - 1);
        const int r0  = y0  - ylo;           // staged index of top row
        const int r1  = y1r - ylo;           // staged index of bottom row

        vf4 tl0, tr0, tl1, tr1, bl0, br0, bl1, br1;

        if (r0 < nst) {                      // wave-uniform
            tl0 = st[r0][sx0][lane];      tr0 = st[r0][sx1][lane];
            tl1 = st[r0][sx0][lane + 64]; tr1 = st[r0][sx1][lane + 64];
        } else {                             // fallback: direct global (rare)
            const vf4* rT = img + (size_t)y0 * ROW4;
            tl0 = rT[x0 * C4 + lane];        tr0 = rT[x1i * C4 + lane];
            tl1 = rT[x0 * C4 + lane + 64];   tr1 = rT[x1i * C4 + lane + 64];
        }
        if (r1 < nst) {                      // wave-uniform
            bl0 = st[r1][sx0][lane];      br0 = st[r1][sx1][lane];
            bl1 = st[r1][sx0][lane + 64]; br1 = st[r1][sx1][lane + 64];
        } else {
            const vf4* rB = img + (size_t)y1r * ROW4;
            bl0 = rB[x0 * C4 + lane];        br0 = rB[x1i * C4 + lane];
            bl1 = rB[x0 * C4 + lane + 64];   br1 = rB[x1i * C4 + lane + 64];
        }

        const vf4 top0 = tl0 + (tr0 - tl0) * lx;
        const vf4 bot0 = bl0 + (br0 - bl0) * lx;
        o0 = top0 + (bot0 - top0) * ly;
        const vf4 top1 = tl1 + (tr1 - tl1) * lx;
        const vf4 bot1 = bl1 + (br1 - bl1) * lx;
        o1 = top1 + (bot1 - top1) * ly;
    } else {
        o0 = (vf4)(0.0f);
        o1 = (vf4)(0.0f);
    }

    // NT stores won the R6 A/B: keep them. 2KB contiguous per wave.
    const int cell = t * (PP * PP) + wid * PP + px;
    vf4* op = ((vf4*)out) + (size_t)cell * C4 + lane;
    __builtin_nontemporal_store(o0, op);
    __builtin_nontemporal_store(o1, op + 64);
}

extern "C" void kernel_launch(void* const* d_in, const int* in_sizes, int n_in,
                              void* d_out, int out_size, void* d_ws, size_t ws_size,
                              hipStream_t stream)
{
    const float* fm  = (const float*)d_in[0];
    const float* nms = (const float*)d_in[1];
    float* out = (float*)d_out;

    roi_stage_kernel<<<NBLK, 448, 0, stream>>>(fm, nms, out);
}

// Round 11
// 37.421 us; speedup vs baseline: 1.5577x; 1.3615x over previous
//
#include <hip/hip_runtime.h>

// feature_map: (B=16, H=27, W=48, C=512) fp32
// nmses:       (B=16, R=100, 4) fp32  (cx, cy, w, h in pixels)
// output:      (B, R, 7, 7, C) fp32
#define BB   16
#define RR   100
#define HH   27
#define WW   48
#define CC   512
#define PP   7

#define C4       (CC / 4)            // 128 float4 per pixel
#define ROW4     (WW * C4)           // 6144 float4 per (b,y)
#define IMG4     (HH * ROW4)         // 165888 float4 per b

#define TOTAL4   (BB * RR * PP * PP * C4)   // 10,035,200 float4
#define NTHREADS (TOTAL4 / 4)               // 4 float4 per thread
#define NBLOCKS  (NTHREADS / 256)           // 9800; 9800 % 8 == 0
#define NXCD     8

typedef float vf4 __attribute__((ext_vector_type(4)));

// Per-cell sampling state (all wave-uniform / scalar).
struct CellS {
    const vf4* rT;
    const vf4* rB;
    int xo0, xo1;        // x0*C4, x1i*C4
    float lx, ly;
    bool valid;
};

__device__ __forceinline__ CellS cell_setup(const float* __restrict__ fm,
                                            const float* __restrict__ nms,
                                            int cell)
{
    CellS s;
    const int px = cell % PP;
    int t        = cell / PP;
    const int py = t % PP;
    t           /= PP;

    const int ts = __builtin_amdgcn_readfirstlane(t);
    const int b  = ts / RR;

    const vf4 box = ((const vf4*)nms)[ts];
    const float cx = box.x, cy = box.y, w = box.z, h = box.w;

    const float x1 = (cx - w * 0.5f) / 768.0f;
    const float x2 = (cx + w * 0.5f) / 768.0f;
    const float y1 = (cy - h * 0.5f) / 432.0f;
    const float y2 = (cy + h * 0.5f) / 432.0f;

    const float ys = y1 * 26.0f + (float)py * (y2 - y1) * 26.0f / 6.0f;
    const float xs = x1 * 47.0f + (float)px * (x2 - x1) * 47.0f / 6.0f;

    s.valid = (ys >= 0.0f) && (ys <= 26.0f) &&
              (xs >= 0.0f) && (xs <= 47.0f);

    const float y0f = floorf(ys);
    const float x0f = floorf(xs);
    s.ly = ys - y0f;
    s.lx = xs - x0f;

    int y0 = (int)y0f; y0 = min(max(y0, 0), HH - 1);
    const int y1i = min(y0 + 1, HH - 1);
    int x0 = (int)x0f; x0 = min(max(x0, 0), WW - 1);
    const int x1i = min(x0 + 1, WW - 1);

    const vf4* img = ((const vf4*)fm) + (size_t)b * IMG4;
    s.rT  = img + y0  * ROW4;
    s.rB  = img + y1i * ROW4;
    s.xo0 = x0  * C4;
    s.xo1 = x1i * C4;
    return s;
}

__global__ __launch_bounds__(256) void roi_crop_resize_kernel(
    const float* __restrict__ fm,
    const float* __restrict__ nms,
    float* __restrict__ out)
{
    // XCD-aware bijective swizzle (NBLOCKS % 8 == 0): contiguous box ranges
    // per XCD keep each XCD's ~2.65MB image slice in its private 4MB L2.
    const int bid  = blockIdx.x;
    const int wgid = (bid % NXCD) * (NBLOCKS / NXCD) + bid / NXCD;

    const int idx   = wgid * 256 + threadIdx.x;  // [0, NTHREADS)
    const int c4    = idx & 63;                  // lane's float4 slot
    const int pair  = idx >> 6;                  // wave handles 2 cells
    const int cell0 = pair * 2;
    const int cell1 = cell0 + 1;

    const CellS s0 = cell_setup(fm, nms, cell0);
    const CellS s1 = cell_setup(fm, nms, cell1);

    // Issue all 16 independent 16B loads before any use (deep MLP).
    vf4 a_tl0, a_tr0, a_bl0, a_br0, a_tl1, a_tr1, a_bl1, a_br1;
    vf4 b_tl0, b_tr0, b_bl0, b_br0, b_tl1, b_tr1, b_bl1, b_br1;

    if (s0.valid) {
        a_tl0 = s0.rT[s0.xo0 + c4];      a_tr0 = s0.rT[s0.xo1 + c4];
        a_bl0 = s0.rB[s0.xo0 + c4];      a_br0 = s0.rB[s0.xo1 + c4];
        a_tl1 = s0.rT[s0.xo0 + c4 + 64]; a_tr1 = s0.rT[s0.xo1 + c4 + 64];
        a_bl1 = s0.rB[s0.xo0 + c4 + 64]; a_br1 = s0.rB[s0.xo1 + c4 + 64];
    }
    if (s1.valid) {
        b_tl0 = s1.rT[s1.xo0 + c4];      b_tr0 = s1.rT[s1.xo1 + c4];
        b_bl0 = s1.rB[s1.xo0 + c4];      b_br0 = s1.rB[s1.xo1 + c4];
        b_tl1 = s1.rT[s1.xo0 + c4 + 64]; b_tr1 = s1.rT[s1.xo1 + c4 + 64];
        b_bl1 = s1.rB[s1.xo0 + c4 + 64]; b_br1 = s1.rB[s1.xo1 + c4 + 64];
    }

    vf4 o00, o01, o10, o11;
    if (s0.valid) {
        const vf4 top0 = a_tl0 + (a_tr0 - a_tl0) * s0.lx;
        const vf4 bot0 = a_bl0 + (a_br0 - a_bl0) * s0.lx;
        o00 = top0 + (bot0 - top0) * s0.ly;
        const vf4 top1 = a_tl1 + (a_tr1 - a_tl1) * s0.lx;
        const vf4 bot1 = a_bl1 + (a_br1 - a_bl1) * s0.lx;
        o01 = top1 + (bot1 - top1) * s0.ly;
    } else {
        o00 = (vf4)(0.0f); o01 = (vf4)(0.0f);
    }
    if (s1.valid) {
        const vf4 top0 = b_tl0 + (b_tr0 - b_tl0) * s1.lx;
        const vf4 bot0 = b_bl0 + (b_br0 - b_bl0) * s1.lx;
        o10 = top0 + (bot0 - top0) * s1.ly;
        const vf4 top1 = b_tl1 + (b_tr1 - b_tl1) * s1.lx;
        const vf4 bot1 = b_bl1 + (b_br1 - b_bl1) * s1.lx;
        o11 = top1 + (bot1 - top1) * s1.ly;
    } else {
        o10 = (vf4)(0.0f); o11 = (vf4)(0.0f);
    }

    // NT stores won the R6 A/B (37.6 vs 39.0): keep them.
    vf4* op = ((vf4*)out) + (size_t)cell0 * C4 + c4;
    __builtin_nontemporal_store(o00, op);
    __builtin_nontemporal_store(o01, op + 64);
    __builtin_nontemporal_store(o10, op + 128);
    __builtin_nontemporal_store(o11, op + 192);
}

extern "C" void kernel_launch(void* const* d_in, const int* in_sizes, int n_in,
                              void* d_out, int out_size, void* d_ws, size_t ws_size,
                              hipStream_t stream)
{
    const float* fm  = (const float*)d_in[0];
    const float* nms = (const float*)d_in[1];
    float* out = (float*)d_out;

    roi_crop_resize_kernel<<<NBLOCKS, 256, 0, stream>>>(fm, nms, out);
}